// Round 1
// baseline (432.170 us; speedup 1.0000x reference)
//
#include <hip/hip_runtime.h>
#include <stdint.h>

typedef unsigned short u16;
typedef __attribute__((ext_vector_type(4))) float f32x4;
typedef __attribute__((ext_vector_type(8))) short bf16x8;
typedef __attribute__((ext_vector_type(4))) unsigned short u16x4;

static __device__ __forceinline__ u16 f2bf(float f) {
  union { float f; unsigned u; } v; v.f = f;
  unsigned r = v.u + 0x7fffu + ((v.u >> 16) & 1u);
  return (u16)(r >> 16);
}

static __device__ __forceinline__ void load_lds16(const void* g, void* l) {
  __builtin_amdgcn_global_load_lds(
      (const __attribute__((address_space(1))) void*)g,
      (__attribute__((address_space(3))) void*)l, 16, 0, 0);
}

// ---------------- conversion kernels ----------------

__global__ __launch_bounds__(256) void cvt_f32_bf16(
    const float* __restrict__ in, u16* __restrict__ out, int n) {
  int i = blockIdx.x * 256 + threadIdx.x;
  const int n4 = n >> 2;
  for (; i < n4; i += gridDim.x * 256) {
    f32x4 v = *(const f32x4*)(in + (size_t)i * 4);
    u16x4 o = { f2bf(v[0]), f2bf(v[1]), f2bf(v[2]), f2bf(v[3]) };
    *(u16x4*)(out + (size_t)i * 4) = o;
  }
}

// concat [Wq(2048); Wk(512); Wv(512)] rows, K=2048, to bf16
__global__ __launch_bounds__(256) void build_wcat(
    const float* __restrict__ Wq, const float* __restrict__ Wk,
    const float* __restrict__ Wv, u16* __restrict__ out) {
  int i = blockIdx.x * 256 + threadIdx.x;
  const int n4 = 3072 * 512;
  for (; i < n4; i += gridDim.x * 256) {
    int row = i >> 9;
    int c4 = i & 511;
    const float* src;
    if (row < 2048)       src = Wq + (size_t)row * 2048;
    else if (row < 2560)  src = Wk + (size_t)(row - 2048) * 2048;
    else                  src = Wv + (size_t)(row - 2560) * 2048;
    f32x4 v = *(const f32x4*)(src + c4 * 4);
    u16x4 o = { f2bf(v[0]), f2bf(v[1]), f2bf(v[2]), f2bf(v[3]) };
    *(u16x4*)(out + (size_t)i * 4) = o;
  }
}

// ---------------- bf16 bt-GEMM (m97 structure): C[M,N] = A[M,K] * B[N,K]^T ----------------

__global__ __launch_bounds__(256) void gemm_bt(
    const u16* __restrict__ A, const u16* __restrict__ B,
    float* __restrict__ C, int M, int N, int K) {
  __shared__ u16 As[128 * 32];
  __shared__ u16 Bs[128 * 32];
  const int tid = threadIdx.x;
  const int bm = blockIdx.y, bn = blockIdx.x;
  const int w = tid >> 6, l = tid & 63;
  const int wr = w >> 1, wc = w & 1;
  const int lr = l & 15, lg = l >> 4;
  f32x4 acc[4][4] = {};
  const int srow = tid >> 2;
  const int scol = (tid & 3) << 3;
  const u16* Ag = A + (size_t)bm * 128 * K + (size_t)srow * K + scol;
  const u16* Bg = B + (size_t)bn * 128 * K + (size_t)srow * K + scol;
  u16* Asl = As + srow * 32 + scol;
  u16* Bsl = Bs + srow * 32 + scol;
  const int nk = K >> 5;
  for (int kt = 0; kt < nk; ++kt) {
    __syncthreads();
    const int ko = kt << 5;
    load_lds16(Ag + ko, Asl);
    load_lds16(Ag + (size_t)64 * K + ko, Asl + 64 * 32);
    load_lds16(Bg + ko, Bsl);
    load_lds16(Bg + (size_t)64 * K + ko, Bsl + 64 * 32);
    __syncthreads();
    bf16x8 af[4], bfr[4];
#pragma unroll
    for (int m = 0; m < 4; ++m)
      af[m] = *(const bf16x8*)&As[(wr * 64 + m * 16 + lr) * 32 + lg * 8];
#pragma unroll
    for (int n = 0; n < 4; ++n)
      bfr[n] = *(const bf16x8*)&Bs[(wc * 64 + n * 16 + lr) * 32 + lg * 8];
#pragma unroll
    for (int m = 0; m < 4; ++m)
#pragma unroll
      for (int n = 0; n < 4; ++n)
        acc[m][n] = __builtin_amdgcn_mfma_f32_16x16x32_bf16(af[m], bfr[n], acc[m][n], 0, 0, 0);
  }
#pragma unroll
  for (int m = 0; m < 4; ++m) {
    const int row = bm * 128 + wr * 64 + m * 16 + lg * 4;
#pragma unroll
    for (int n = 0; n < 4; ++n) {
      const int col = bn * 128 + wc * 64 + n * 16 + lr;
#pragma unroll
      for (int r = 0; r < 4; ++r)
        C[(size_t)(row + r) * N + col] = acc[m][n][r];
    }
  }
}

// ---------------- per-head RMSNorm + RoPE ----------------
// one wave per (b,t,slot); slot 0..15 = q heads, 16..19 = k heads
__global__ __launch_bounds__(256) void norm_rope(
    const float* __restrict__ qkv, const float* __restrict__ qn_w,
    const float* __restrict__ kn_w, const float* __restrict__ cosb,
    const float* __restrict__ sinb, u16* __restrict__ qhat,
    u16* __restrict__ khat) {
  const int gw = (blockIdx.x * 256 + threadIdx.x) >> 6;
  const int lane = threadIdx.x & 63;
  const int slot = gw % 20;
  const int row = gw / 20;  // b*2048 + t
  const int t = row & 2047;
  const int b = row >> 11;
  const float* src; const float* nw; u16* dst;
  bool isq = slot < 16;
  if (isq) {
    src = qkv + (size_t)row * 3072 + slot * 128;
    nw = qn_w;
    dst = qhat + ((size_t)(b * 16 + slot) * 2048 + t) * 128;
  } else {
    src = qkv + (size_t)row * 3072 + 2048 + (slot - 16) * 128;
    nw = kn_w;
    dst = khat + ((size_t)(b * 4 + (slot - 16)) * 2048 + t) * 128;
  }
  float x1 = src[lane], x2 = src[lane + 64];
  float ss = x1 * x1 + x2 * x2;
#pragma unroll
  for (int o = 32; o; o >>= 1) ss += __shfl_xor(ss, o);
  float rs = rsqrtf(ss * (1.0f / 128.0f) + 1e-6f);
  float h1 = x1 * rs * nw[lane];
  float h2 = x2 * rs * nw[lane + 64];
  float c = cosb[t * 128 + lane], s = sinb[t * 128 + lane];
  float o1 = h1 * c - h2 * s;
  float o2 = h2 * c + h1 * s;
  if (isq) { o1 *= 0.088388347648318447f; o2 *= 0.088388347648318447f; }
  dst[lane] = f2bf(o1);
  dst[lane + 64] = f2bf(o2);
}

// ---------------- V transpose: qkv fp32 [.,3072] v-cols -> vT bf16 [B,KV,D,T] ----------------
__global__ __launch_bounds__(256) void v_trans(
    const float* __restrict__ qkv, u16* __restrict__ vT) {
  __shared__ u16 st[64][130];
  const int bi = blockIdx.x;  // b*128 + kv*32 + tt
  const int tt = bi & 31;
  const int kv = (bi >> 5) & 3;
  const int b = bi >> 7;
  const int tid = threadIdx.x;
#pragma unroll
  for (int i = 0; i < 32; ++i) {
    int idx = i * 256 + tid;
    int t = idx >> 7, d = idx & 127;
    float v = qkv[(size_t)(b * 2048 + tt * 64 + t) * 3072 + 2560 + kv * 128 + d];
    st[t][d] = f2bf(v);
  }
  __syncthreads();
#pragma unroll
  for (int i = 0; i < 32; ++i) {
    int idx = i * 256 + tid;
    int d = idx >> 6, t = idx & 63;
    vT[((size_t)(b * 4 + kv) * 128 + d) * 2048 + tt * 64 + t] = st[t][d];
  }
}

// ---------------- causal GQA flash attention ----------------
// block = 4 waves; each wave owns 16 q rows; KV tiles of 64
__global__ __launch_bounds__(256) void attn(
    const u16* __restrict__ qhat, const u16* __restrict__ khat,
    const u16* __restrict__ vT, u16* __restrict__ yb) {
  __shared__ u16 Kt[64 * 128];
  __shared__ u16 Vt[128 * 64];
  __shared__ u16 Pl[4][16 * 64];
  const int bi = blockIdx.x;
  const int qt = bi & 31;
  const int h = (bi >> 5) & 15;
  const int b = bi >> 9;
  const int kvh = h >> 2;
  const int tid = threadIdx.x;
  const int w = tid >> 6, l = tid & 63;
  const int lr = l & 15, lg = l >> 4;
  const int q0 = qt * 64;

  bf16x8 qf[4];
  const u16* qp = qhat + ((size_t)(b * 16 + h) * 2048 + q0 + w * 16 + lr) * 128;
#pragma unroll
  for (int kc = 0; kc < 4; ++kc)
    qf[kc] = *(const bf16x8*)(qp + kc * 32 + lg * 8);

  f32x4 yacc[8] = {};
  float mrow[4], lrow[4];
#pragma unroll
  for (int r = 0; r < 4; ++r) { mrow[r] = -1e30f; lrow[r] = 0.f; }

  const u16* Kg = khat + (size_t)(b * 4 + kvh) * 2048 * 128;
  const u16* Vg = vT + (size_t)(b * 4 + kvh) * 128 * 2048;
  const int nt = qt + 1;
  for (int tile = 0; tile < nt; ++tile) {
    const int kv0 = tile * 64;
    __syncthreads();
#pragma unroll
    for (int c = 0; c < 4; ++c)
      load_lds16(Kg + (size_t)(kv0 + c * 16 + (tid >> 4)) * 128 + (tid & 15) * 8,
                 Kt + c * 2048 + tid * 8);
#pragma unroll
    for (int c = 0; c < 4; ++c)
      load_lds16(Vg + (size_t)(c * 32 + (tid >> 3)) * 2048 + kv0 + (tid & 7) * 8,
                 Vt + c * 2048 + tid * 8);
    __syncthreads();
    // QK^T
    f32x4 sacc[4] = {};
#pragma unroll
    for (int kc = 0; kc < 4; ++kc) {
#pragma unroll
      for (int n = 0; n < 4; ++n) {
        bf16x8 kf = *(const bf16x8*)&Kt[(n * 16 + lr) * 128 + kc * 32 + lg * 8];
        sacc[n] = __builtin_amdgcn_mfma_f32_16x16x32_bf16(qf[kc], kf, sacc[n], 0, 0, 0);
      }
    }
    // causal mask on diagonal tile
    if (tile == nt - 1) {
#pragma unroll
      for (int n = 0; n < 4; ++n) {
        int kvcol = kv0 + n * 16 + lr;
#pragma unroll
        for (int r = 0; r < 4; ++r) {
          int qrow = q0 + w * 16 + lg * 4 + r;
          if (kvcol > qrow) sacc[n][r] = -1e30f;
        }
      }
    }
    // online softmax (rows lg*4+r; reduce over 16-lane groups)
    float scale_r[4];
#pragma unroll
    for (int r = 0; r < 4; ++r) {
      float mx = fmaxf(fmaxf(sacc[0][r], sacc[1][r]), fmaxf(sacc[2][r], sacc[3][r]));
#pragma unroll
      for (int o = 8; o; o >>= 1) mx = fmaxf(mx, __shfl_xor(mx, o));
      float mnew = fmaxf(mrow[r], mx);
      scale_r[r] = __expf(mrow[r] - mnew);
      mrow[r] = mnew;
    }
#pragma unroll
    for (int n = 0; n < 4; ++n)
#pragma unroll
      for (int r = 0; r < 4; ++r)
        sacc[n][r] = __expf(sacc[n][r] - mrow[r]);
#pragma unroll
    for (int r = 0; r < 4; ++r) {
      float sm = sacc[0][r] + sacc[1][r] + sacc[2][r] + sacc[3][r];
#pragma unroll
      for (int o = 8; o; o >>= 1) sm += __shfl_xor(sm, o);
      lrow[r] = lrow[r] * scale_r[r] + sm;
    }
#pragma unroll
    for (int n = 0; n < 8; ++n)
#pragma unroll
      for (int r = 0; r < 4; ++r) yacc[n][r] *= scale_r[r];
    // write P (bf16) to per-wave LDS
#pragma unroll
    for (int n = 0; n < 4; ++n)
#pragma unroll
      for (int r = 0; r < 4; ++r)
        Pl[w][(lg * 4 + r) * 64 + n * 16 + lr] = f2bf(sacc[n][r]);
    __syncthreads();
    // PV
#pragma unroll
    for (int kk = 0; kk < 2; ++kk) {
      bf16x8 pf = *(const bf16x8*)&Pl[w][lr * 64 + kk * 32 + lg * 8];
#pragma unroll
      for (int n = 0; n < 8; ++n) {
        bf16x8 vf = *(const bf16x8*)&Vt[(n * 16 + lr) * 64 + kk * 32 + lg * 8];
        yacc[n] = __builtin_amdgcn_mfma_f32_16x16x32_bf16(pf, vf, yacc[n], 0, 0, 0);
      }
    }
  }
  // epilogue: y[b*T+t][h*128+d] bf16
#pragma unroll
  for (int r = 0; r < 4; ++r) {
    const int row = q0 + w * 16 + lg * 4 + r;
    float inv = 1.0f / lrow[r];
    u16* yp = yb + ((size_t)(b * 2048) + row) * 2048 + h * 128;
#pragma unroll
    for (int n = 0; n < 8; ++n)
      yp[n * 16 + lr] = f2bf(yacc[n][r] * inv);
  }
}

// ---------------- launcher ----------------

extern "C" void kernel_launch(void* const* d_in, const int* in_sizes, int n_in,
                              void* d_out, int out_size, void* d_ws, size_t ws_size,
                              hipStream_t stream) {
  const float* x    = (const float*)d_in[0];
  const float* Wq   = (const float*)d_in[1];
  const float* Wk   = (const float*)d_in[2];
  const float* Wv   = (const float*)d_in[3];
  const float* Wo   = (const float*)d_in[4];
  const float* qn   = (const float*)d_in[5];
  const float* kn   = (const float*)d_in[6];
  const float* cosb = (const float*)d_in[7];
  const float* sinb = (const float*)d_in[8];
  float* out = (float*)d_out;
  (void)in_sizes; (void)n_in; (void)out_size; (void)ws_size;

  char* p = (char*)d_ws;
  u16*   xb   = (u16*)p;   p += (size_t)8388608 * 2;    // x bf16 [4096,2048]
  u16*   wcat = (u16*)p;   p += (size_t)6291456 * 2;    // [3072,2048]
  u16*   wob  = (u16*)p;   p += (size_t)4194304 * 2;    // [2048,2048]
  float* qkvf = (float*)p; p += (size_t)12582912 * 4;   // [4096,3072] fp32
  u16*   qh   = (u16*)p;   p += (size_t)8388608 * 2;    // [2,16,2048,128]
  u16*   kh   = (u16*)p;   p += (size_t)2097152 * 2;    // [2,4,2048,128]
  u16*   vt   = (u16*)p;   p += (size_t)2097152 * 2;    // [2,4,128,2048]
  u16*   yb   = (u16*)p;   p += (size_t)8388608 * 2;    // [4096,2048]

  cvt_f32_bf16<<<2048, 256, 0, stream>>>(x, xb, 8388608);
  build_wcat<<<2048, 256, 0, stream>>>(Wq, Wk, Wv, wcat);
  cvt_f32_bf16<<<2048, 256, 0, stream>>>(Wo, wob, 4194304);
  gemm_bt<<<dim3(24, 32), 256, 0, stream>>>(xb, wcat, qkvf, 4096, 3072, 2048);
  norm_rope<<<20480, 256, 0, stream>>>(qkvf, qn, kn, cosb, sinb, qh, kh);
  v_trans<<<256, 256, 0, stream>>>(qkvf, vt);
  attn<<<1024, 256, 0, stream>>>(qh, kh, vt, yb);
  gemm_bt<<<dim3(16, 32), 256, 0, stream>>>(yb, wob, out, 4096, 2048, 2048);
}

// Round 2
// 357.783 us; speedup vs baseline: 1.2079x; 1.2079x over previous
//
#include <hip/hip_runtime.h>
#include <stdint.h>

typedef unsigned short u16;
typedef __attribute__((ext_vector_type(4))) float f32x4;
typedef __attribute__((ext_vector_type(8))) short bf16x8;
typedef __attribute__((ext_vector_type(4))) unsigned short u16x4;

static __device__ __forceinline__ u16 f2bf(float f) {
  union { float f; unsigned u; } v; v.f = f;
  unsigned r = v.u + 0x7fffu + ((v.u >> 16) & 1u);
  return (u16)(r >> 16);
}

static __device__ __forceinline__ void load_lds16(const void* g, void* l) {
  __builtin_amdgcn_global_load_lds(
      (const __attribute__((address_space(1))) void*)g,
      (__attribute__((address_space(3))) void*)l, 16, 0, 0);
}

// ---------------- conversion kernels ----------------

__global__ __launch_bounds__(256) void cvt_f32_bf16(
    const float* __restrict__ in, u16* __restrict__ out, int n) {
  int i = blockIdx.x * 256 + threadIdx.x;
  const int n4 = n >> 2;
  for (; i < n4; i += gridDim.x * 256) {
    f32x4 v = *(const f32x4*)(in + (size_t)i * 4);
    u16x4 o = { f2bf(v[0]), f2bf(v[1]), f2bf(v[2]), f2bf(v[3]) };
    *(u16x4*)(out + (size_t)i * 4) = o;
  }
}

// concat [Wq(2048); Wk(512); Wv(512)] rows, K=2048, to bf16
__global__ __launch_bounds__(256) void build_wcat(
    const float* __restrict__ Wq, const float* __restrict__ Wk,
    const float* __restrict__ Wv, u16* __restrict__ out) {
  int i = blockIdx.x * 256 + threadIdx.x;
  const int n4 = 3072 * 512;
  for (; i < n4; i += gridDim.x * 256) {
    int row = i >> 9;
    int c4 = i & 511;
    const float* src;
    if (row < 2048)       src = Wq + (size_t)row * 2048;
    else if (row < 2560)  src = Wk + (size_t)(row - 2048) * 2048;
    else                  src = Wv + (size_t)(row - 2560) * 2048;
    f32x4 v = *(const f32x4*)(src + c4 * 4);
    u16x4 o = { f2bf(v[0]), f2bf(v[1]), f2bf(v[2]), f2bf(v[3]) };
    *(u16x4*)(out + (size_t)i * 4) = o;
  }
}

// ---------------- bf16 bt-GEMM (m97 structure): C[M,N] = A[M,K] * B[N,K]^T ----------------

__global__ __launch_bounds__(256) void gemm_bt(
    const u16* __restrict__ A, const u16* __restrict__ B,
    float* __restrict__ C, int M, int N, int K) {
  __shared__ u16 As[128 * 32];
  __shared__ u16 Bs[128 * 32];
  const int tid = threadIdx.x;
  const int bm = blockIdx.y, bn = blockIdx.x;
  const int w = tid >> 6, l = tid & 63;
  const int wr = w >> 1, wc = w & 1;
  const int lr = l & 15, lg = l >> 4;
  f32x4 acc[4][4] = {};
  const int srow = tid >> 2;
  const int scol = (tid & 3) << 3;
  const u16* Ag = A + (size_t)bm * 128 * K + (size_t)srow * K + scol;
  const u16* Bg = B + (size_t)bn * 128 * K + (size_t)srow * K + scol;
  u16* Asl = As + srow * 32 + scol;
  u16* Bsl = Bs + srow * 32 + scol;
  const int nk = K >> 5;
  for (int kt = 0; kt < nk; ++kt) {
    __syncthreads();
    const int ko = kt << 5;
    load_lds16(Ag + ko, Asl);
    load_lds16(Ag + (size_t)64 * K + ko, Asl + 64 * 32);
    load_lds16(Bg + ko, Bsl);
    load_lds16(Bg + (size_t)64 * K + ko, Bsl + 64 * 32);
    __syncthreads();
    bf16x8 af[4], bfr[4];
#pragma unroll
    for (int m = 0; m < 4; ++m)
      af[m] = *(const bf16x8*)&As[(wr * 64 + m * 16 + lr) * 32 + lg * 8];
#pragma unroll
    for (int n = 0; n < 4; ++n)
      bfr[n] = *(const bf16x8*)&Bs[(wc * 64 + n * 16 + lr) * 32 + lg * 8];
#pragma unroll
    for (int m = 0; m < 4; ++m)
#pragma unroll
      for (int n = 0; n < 4; ++n)
        acc[m][n] = __builtin_amdgcn_mfma_f32_16x16x32_bf16(af[m], bfr[n], acc[m][n], 0, 0, 0);
  }
#pragma unroll
  for (int m = 0; m < 4; ++m) {
    const int row = bm * 128 + wr * 64 + m * 16 + lg * 4;
#pragma unroll
    for (int n = 0; n < 4; ++n) {
      const int col = bn * 128 + wc * 64 + n * 16 + lr;
#pragma unroll
      for (int r = 0; r < 4; ++r)
        C[(size_t)(row + r) * N + col] = acc[m][n][r];
    }
  }
}

// ---------------- per-head RMSNorm + RoPE ----------------
__global__ __launch_bounds__(256) void norm_rope(
    const float* __restrict__ qkv, const float* __restrict__ qn_w,
    const float* __restrict__ kn_w, const float* __restrict__ cosb,
    const float* __restrict__ sinb, u16* __restrict__ qhat,
    u16* __restrict__ khat) {
  const int gw = (blockIdx.x * 256 + threadIdx.x) >> 6;
  const int lane = threadIdx.x & 63;
  const int slot = gw % 20;
  const int row = gw / 20;  // b*2048 + t
  const int t = row & 2047;
  const int b = row >> 11;
  const float* src; const float* nw; u16* dst;
  bool isq = slot < 16;
  if (isq) {
    src = qkv + (size_t)row * 3072 + slot * 128;
    nw = qn_w;
    dst = qhat + ((size_t)(b * 16 + slot) * 2048 + t) * 128;
  } else {
    src = qkv + (size_t)row * 3072 + 2048 + (slot - 16) * 128;
    nw = kn_w;
    dst = khat + ((size_t)(b * 4 + (slot - 16)) * 2048 + t) * 128;
  }
  float x1 = src[lane], x2 = src[lane + 64];
  float ss = x1 * x1 + x2 * x2;
#pragma unroll
  for (int o = 32; o; o >>= 1) ss += __shfl_xor(ss, o);
  float rs = rsqrtf(ss * (1.0f / 128.0f) + 1e-6f);
  float h1 = x1 * rs * nw[lane];
  float h2 = x2 * rs * nw[lane + 64];
  float c = cosb[t * 128 + lane], s = sinb[t * 128 + lane];
  float o1 = h1 * c - h2 * s;
  float o2 = h2 * c + h1 * s;
  if (isq) { o1 *= 0.088388347648318447f; o2 *= 0.088388347648318447f; }
  dst[lane] = f2bf(o1);
  dst[lane + 64] = f2bf(o2);
}

// ---------------- V transpose: qkv fp32 [.,3072] v-cols -> vT bf16 [B,KV,D,T] ----------------
__global__ __launch_bounds__(256) void v_trans(
    const float* __restrict__ qkv, u16* __restrict__ vT) {
  __shared__ u16 st[64][130];
  const int bi = blockIdx.x;  // b*128 + kv*32 + tt
  const int tt = bi & 31;
  const int kv = (bi >> 5) & 3;
  const int b = bi >> 7;
  const int tid = threadIdx.x;
#pragma unroll
  for (int i = 0; i < 32; ++i) {
    int idx = i * 256 + tid;
    int t = idx >> 7, d = idx & 127;
    float v = qkv[(size_t)(b * 2048 + tt * 64 + t) * 3072 + 2560 + kv * 128 + d];
    st[t][d] = f2bf(v);
  }
  __syncthreads();
#pragma unroll
  for (int i = 0; i < 32; ++i) {
    int idx = i * 256 + tid;
    int d = idx >> 6, t = idx & 63;
    vT[((size_t)(b * 4 + kv) * 128 + d) * 2048 + tt * 64 + t] = st[t][d];
  }
}

// ---------------- causal GQA flash attention ----------------
// 4 waves; each wave owns 16 q rows; KV tiles of 64.
// K double-buffered in LDS (XOR-swizzled via pre-swizzled global src),
// V read direct from L2 into register fragments, P in wave-private swizzled LDS.
// 1 barrier per KV tile.
__global__ __launch_bounds__(256, 3) void attn(
    const u16* __restrict__ qhat, const u16* __restrict__ khat,
    const u16* __restrict__ vT, u16* __restrict__ yb) {
  __shared__ u16 Kt[2][64 * 128];
  __shared__ u16 Pl[4][16 * 64];
  // ---- balanced block remap: co-resident blocks {j, j+256, ...} get qt sums == const
  const int bi = blockIdx.x;
  const int g = bi >> 8, j = bi & 255;
  int base = ((j & 31) + ((g >> 1) << 3)) & 31;
  const int qt = (g & 1) ? (31 - base) : base;
  const int rest = (g << 3) | (j >> 5);  // b*16 + h
  const int h = rest & 15, b = rest >> 4;
  const int kvh = h >> 2;
  const int tid = threadIdx.x;
  const int w = tid >> 6, l = tid & 63;
  const int lr = l & 15, lg = l >> 4;
  const int q0 = qt * 64;

  bf16x8 qf[4];
  const u16* qp = qhat + ((size_t)(b * 16 + h) * 2048 + q0 + w * 16 + lr) * 128;
#pragma unroll
  for (int kc = 0; kc < 4; ++kc)
    qf[kc] = *(const bf16x8*)(qp + kc * 32 + lg * 8);

  f32x4 yacc[8] = {};
  float mrow[4], lrow[4];
#pragma unroll
  for (int r = 0; r < 4; ++r) { mrow[r] = -1e30f; lrow[r] = 0.f; }

  const u16* Kg = khat + (size_t)(b * 4 + kvh) * 2048 * 128;
  const u16* Vg = vT + (size_t)(b * 4 + kvh) * 128 * 2048;
  const int nt = qt + 1;
  const int srow = tid >> 4;        // 0..15
  const int schunk = tid & 15;      // 16B chunk within 256B row

  // prologue: stage K tile 0 into buf 0 (source pre-swizzled, LDS dest linear)
#pragma unroll
  for (int c = 0; c < 4; ++c) {
    int r = c * 16 + srow;
    int col16 = schunk ^ (r & 7);
    load_lds16(Kg + (size_t)r * 128 + col16 * 8, &Kt[0][c * 2048 + tid * 8]);
  }
  int cur = 0;
  for (int tile = 0; tile < nt; ++tile) {
    const int kv0 = tile * 64;
    __syncthreads();  // implicit vmcnt drain: Kt[cur] ready & visible
    // prefetch K(t+1) into the other buffer (overlaps whole tile's compute)
    if (tile + 1 < nt) {
#pragma unroll
      for (int c = 0; c < 4; ++c) {
        int r = c * 16 + srow;
        int col16 = schunk ^ (r & 7);
        load_lds16(Kg + (size_t)(kv0 + 64 + r) * 128 + col16 * 8,
                   &Kt[cur ^ 1][c * 2048 + tid * 8]);
      }
    }
    // V fragments (kk=0) straight from L2 into registers
    bf16x8 v0[8], v1[8];
#pragma unroll
    for (int n = 0; n < 8; ++n)
      v0[n] = *(const bf16x8*)(Vg + (size_t)(n * 16 + lr) * 2048 + kv0 + lg * 8);
    // QK^T from Kt[cur] (swizzled reads)
    const u16* Kc = Kt[cur];
    f32x4 sacc[4] = {};
#pragma unroll
    for (int kc = 0; kc < 4; ++kc) {
#pragma unroll
      for (int n = 0; n < 4; ++n) {
        int r = n * 16 + lr;
        bf16x8 kf = *(const bf16x8*)&Kc[r * 128 + ((kc * 32 + lg * 8) ^ ((r & 7) << 3))];
        sacc[n] = __builtin_amdgcn_mfma_f32_16x16x32_bf16(qf[kc], kf, sacc[n], 0, 0, 0);
      }
    }
    // causal mask on diagonal tile
    if (tile == nt - 1) {
#pragma unroll
      for (int n = 0; n < 4; ++n) {
        int kvcol = kv0 + n * 16 + lr;
#pragma unroll
        for (int r = 0; r < 4; ++r) {
          int qrow = q0 + w * 16 + lg * 4 + r;
          if (kvcol > qrow) sacc[n][r] = -1e30f;
        }
      }
    }
    // online softmax (rows lg*4+r; reduce across the 16 lr lanes)
    float scale_r[4];
#pragma unroll
    for (int r = 0; r < 4; ++r) {
      float mx = fmaxf(fmaxf(sacc[0][r], sacc[1][r]), fmaxf(sacc[2][r], sacc[3][r]));
#pragma unroll
      for (int o = 8; o; o >>= 1) mx = fmaxf(mx, __shfl_xor(mx, o));
      float mnew = fmaxf(mrow[r], mx);
      scale_r[r] = __expf(mrow[r] - mnew);
      mrow[r] = mnew;
    }
#pragma unroll
    for (int n = 0; n < 4; ++n)
#pragma unroll
      for (int r = 0; r < 4; ++r)
        sacc[n][r] = __expf(sacc[n][r] - mrow[r]);
#pragma unroll
    for (int r = 0; r < 4; ++r) {
      float sm = sacc[0][r] + sacc[1][r] + sacc[2][r] + sacc[3][r];
#pragma unroll
      for (int o = 8; o; o >>= 1) sm += __shfl_xor(sm, o);
      lrow[r] = lrow[r] * scale_r[r] + sm;
    }
#pragma unroll
    for (int n = 0; n < 8; ++n)
#pragma unroll
      for (int r = 0; r < 4; ++r) yacc[n][r] *= scale_r[r];
    // write P (bf16, swizzled) to wave-private LDS — no barrier needed
#pragma unroll
    for (int n = 0; n < 4; ++n)
#pragma unroll
      for (int r = 0; r < 4; ++r) {
        int prow = lg * 4 + r;
        Pl[w][prow * 64 + ((n * 16 + lr) ^ ((prow & 7) << 3))] = f2bf(sacc[n][r]);
      }
    // V fragments (kk=1) — latency hides under PV kk=0
#pragma unroll
    for (int n = 0; n < 8; ++n)
      v1[n] = *(const bf16x8*)(Vg + (size_t)(n * 16 + lr) * 2048 + kv0 + 32 + lg * 8);
    // PV
    {
      bf16x8 pf0 = *(const bf16x8*)&Pl[w][lr * 64 + ((lg * 8) ^ ((lr & 7) << 3))];
#pragma unroll
      for (int n = 0; n < 8; ++n)
        yacc[n] = __builtin_amdgcn_mfma_f32_16x16x32_bf16(pf0, v0[n], yacc[n], 0, 0, 0);
      bf16x8 pf1 = *(const bf16x8*)&Pl[w][lr * 64 + ((32 + lg * 8) ^ ((lr & 7) << 3))];
#pragma unroll
      for (int n = 0; n < 8; ++n)
        yacc[n] = __builtin_amdgcn_mfma_f32_16x16x32_bf16(pf1, v1[n], yacc[n], 0, 0, 0);
    }
    cur ^= 1;
  }
  // epilogue: y[b*T+t][h*128+d] bf16
#pragma unroll
  for (int r = 0; r < 4; ++r) {
    const int row = q0 + w * 16 + lg * 4 + r;
    float inv = 1.0f / lrow[r];
    u16* yp = yb + ((size_t)(b * 2048) + row) * 2048 + h * 128;
#pragma unroll
    for (int n = 0; n < 8; ++n)
      yp[n * 16 + lr] = f2bf(yacc[n][r] * inv);
  }
}

// ---------------- launcher ----------------

extern "C" void kernel_launch(void* const* d_in, const int* in_sizes, int n_in,
                              void* d_out, int out_size, void* d_ws, size_t ws_size,
                              hipStream_t stream) {
  const float* x    = (const float*)d_in[0];
  const float* Wq   = (const float*)d_in[1];
  const float* Wk   = (const float*)d_in[2];
  const float* Wv   = (const float*)d_in[3];
  const float* Wo   = (const float*)d_in[4];
  const float* qn   = (const float*)d_in[5];
  const float* kn   = (const float*)d_in[6];
  const float* cosb = (const float*)d_in[7];
  const float* sinb = (const float*)d_in[8];
  float* out = (float*)d_out;
  (void)in_sizes; (void)n_in; (void)out_size; (void)ws_size;

  char* p = (char*)d_ws;
  u16*   xb   = (u16*)p;   p += (size_t)8388608 * 2;    // x bf16 [4096,2048]
  u16*   wcat = (u16*)p;   p += (size_t)6291456 * 2;    // [3072,2048]
  u16*   wob  = (u16*)p;   p += (size_t)4194304 * 2;    // [2048,2048]
  float* qkvf = (float*)p; p += (size_t)12582912 * 4;   // [4096,3072] fp32
  u16*   qh   = (u16*)p;   p += (size_t)8388608 * 2;    // [2,16,2048,128]
  u16*   kh   = (u16*)p;   p += (size_t)2097152 * 2;    // [2,4,2048,128]
  u16*   vt   = (u16*)p;   p += (size_t)2097152 * 2;    // [2,4,128,2048]
  u16*   yb   = (u16*)p;   p += (size_t)8388608 * 2;    // [4096,2048]

  cvt_f32_bf16<<<2048, 256, 0, stream>>>(x, xb, 8388608);
  build_wcat<<<2048, 256, 0, stream>>>(Wq, Wk, Wv, wcat);
  cvt_f32_bf16<<<2048, 256, 0, stream>>>(Wo, wob, 4194304);
  gemm_bt<<<dim3(24, 32), 256, 0, stream>>>(xb, wcat, qkvf, 4096, 3072, 2048);
  norm_rope<<<20480, 256, 0, stream>>>(qkvf, qn, kn, cosb, sinb, qh, kh);
  v_trans<<<256, 256, 0, stream>>>(qkvf, vt);
  attn<<<1024, 256, 0, stream>>>(qh, kh, vt, yb);
  gemm_bt<<<dim3(16, 32), 256, 0, stream>>>(yb, wob, out, 4096, 2048, 2048);
}

// Round 4
// 265.472 us; speedup vs baseline: 1.6279x; 1.3477x over previous
//
#include <hip/hip_runtime.h>
#include <stdint.h>

typedef unsigned short u16;
typedef __attribute__((ext_vector_type(4))) float f32x4;
typedef __attribute__((ext_vector_type(16))) float f32x16;
typedef __attribute__((ext_vector_type(8))) short bf16x8;
typedef __attribute__((ext_vector_type(4))) unsigned short u16x4;
typedef __attribute__((ext_vector_type(4))) unsigned u32x4;

static __device__ __forceinline__ u16 f2bf(float f) {
  union { float f; unsigned u; } v; v.f = f;
  unsigned r = v.u + 0x7fffu + ((v.u >> 16) & 1u);
  return (u16)(r >> 16);
}

static __device__ __forceinline__ unsigned cvtpk(float lo, float hi) {
  unsigned r;
  asm("v_cvt_pk_bf16_f32 %0, %1, %2" : "=v"(r) : "v"(lo), "v"(hi));
  return r;
}

// exchanges a's upper 32 lanes with b's lower 32 lanes
static __device__ __forceinline__ void plane32_swap(unsigned& a, unsigned& b) {
  asm volatile("v_permlane32_swap_b32 %0, %1" : "+v"(a), "+v"(b));
}

static __device__ __forceinline__ void load_lds16(const void* g, void* l) {
  __builtin_amdgcn_global_load_lds(
      (const __attribute__((address_space(1))) void*)g,
      (__attribute__((address_space(3))) void*)l, 16, 0, 0);
}

// ---------------- conversion kernels ----------------

__global__ __launch_bounds__(256) void cvt_f32_bf16(
    const float* __restrict__ in, u16* __restrict__ out, int n) {
  int i = blockIdx.x * 256 + threadIdx.x;
  const int n4 = n >> 2;
  for (; i < n4; i += gridDim.x * 256) {
    f32x4 v = *(const f32x4*)(in + (size_t)i * 4);
    u16x4 o = { f2bf(v[0]), f2bf(v[1]), f2bf(v[2]), f2bf(v[3]) };
    *(u16x4*)(out + (size_t)i * 4) = o;
  }
}

__global__ __launch_bounds__(256) void build_wcat(
    const float* __restrict__ Wq, const float* __restrict__ Wk,
    const float* __restrict__ Wv, u16* __restrict__ out) {
  int i = blockIdx.x * 256 + threadIdx.x;
  const int n4 = 3072 * 512;
  for (; i < n4; i += gridDim.x * 256) {
    int row = i >> 9;
    int c4 = i & 511;
    const float* src;
    if (row < 2048)       src = Wq + (size_t)row * 2048;
    else if (row < 2560)  src = Wk + (size_t)(row - 2048) * 2048;
    else                  src = Wv + (size_t)(row - 2560) * 2048;
    f32x4 v = *(const f32x4*)(src + c4 * 4);
    u16x4 o = { f2bf(v[0]), f2bf(v[1]), f2bf(v[2]), f2bf(v[3]) };
    *(u16x4*)(out + (size_t)i * 4) = o;
  }
}

// ---------------- bf16 bt-GEMM (m97 structure): C[M,N] = A[M,K] * B[N,K]^T ----------------

__global__ __launch_bounds__(256) void gemm_bt(
    const u16* __restrict__ A, const u16* __restrict__ B,
    float* __restrict__ C, int M, int N, int K) {
  __shared__ u16 As[128 * 32];
  __shared__ u16 Bs[128 * 32];
  const int tid = threadIdx.x;
  const int bm = blockIdx.y, bn = blockIdx.x;
  const int w = tid >> 6, l = tid & 63;
  const int wr = w >> 1, wc = w & 1;
  const int lr = l & 15, lg = l >> 4;
  f32x4 acc[4][4] = {};
  const int srow = tid >> 2;
  const int scol = (tid & 3) << 3;
  const u16* Ag = A + (size_t)bm * 128 * K + (size_t)srow * K + scol;
  const u16* Bg = B + (size_t)bn * 128 * K + (size_t)srow * K + scol;
  u16* Asl = As + srow * 32 + scol;
  u16* Bsl = Bs + srow * 32 + scol;
  const int nk = K >> 5;
  for (int kt = 0; kt < nk; ++kt) {
    __syncthreads();
    const int ko = kt << 5;
    load_lds16(Ag + ko, Asl);
    load_lds16(Ag + (size_t)64 * K + ko, Asl + 64 * 32);
    load_lds16(Bg + ko, Bsl);
    load_lds16(Bg + (size_t)64 * K + ko, Bsl + 64 * 32);
    __syncthreads();
    bf16x8 af[4], bfr[4];
#pragma unroll
    for (int m = 0; m < 4; ++m)
      af[m] = *(const bf16x8*)&As[(wr * 64 + m * 16 + lr) * 32 + lg * 8];
#pragma unroll
    for (int n = 0; n < 4; ++n)
      bfr[n] = *(const bf16x8*)&Bs[(wc * 64 + n * 16 + lr) * 32 + lg * 8];
#pragma unroll
    for (int m = 0; m < 4; ++m)
#pragma unroll
      for (int n = 0; n < 4; ++n)
        acc[m][n] = __builtin_amdgcn_mfma_f32_16x16x32_bf16(af[m], bfr[n], acc[m][n], 0, 0, 0);
  }
#pragma unroll
  for (int m = 0; m < 4; ++m) {
    const int row = bm * 128 + wr * 64 + m * 16 + lg * 4;
#pragma unroll
    for (int n = 0; n < 4; ++n) {
      const int col = bn * 128 + wc * 64 + n * 16 + lr;
#pragma unroll
      for (int r = 0; r < 4; ++r)
        C[(size_t)(row + r) * N + col] = acc[m][n][r];
    }
  }
}

// ---------------- per-head RMSNorm + RoPE ----------------
__global__ __launch_bounds__(256) void norm_rope(
    const float* __restrict__ qkv, const float* __restrict__ qn_w,
    const float* __restrict__ kn_w, const float* __restrict__ cosb,
    const float* __restrict__ sinb, u16* __restrict__ qhat,
    u16* __restrict__ khat) {
  const int gw = (blockIdx.x * 256 + threadIdx.x) >> 6;
  const int lane = threadIdx.x & 63;
  const int slot = gw % 20;
  const int row = gw / 20;  // b*2048 + t
  const int t = row & 2047;
  const int b = row >> 11;
  const float* src; const float* nw; u16* dst;
  bool isq = slot < 16;
  if (isq) {
    src = qkv + (size_t)row * 3072 + slot * 128;
    nw = qn_w;
    dst = qhat + ((size_t)(b * 16 + slot) * 2048 + t) * 128;
  } else {
    src = qkv + (size_t)row * 3072 + 2048 + (slot - 16) * 128;
    nw = kn_w;
    dst = khat + ((size_t)(b * 4 + (slot - 16)) * 2048 + t) * 128;
  }
  float x1 = src[lane], x2 = src[lane + 64];
  float ss = x1 * x1 + x2 * x2;
#pragma unroll
  for (int o = 32; o; o >>= 1) ss += __shfl_xor(ss, o);
  float rs = rsqrtf(ss * (1.0f / 128.0f) + 1e-6f);
  float h1 = x1 * rs * nw[lane];
  float h2 = x2 * rs * nw[lane + 64];
  float c = cosb[t * 128 + lane], s = sinb[t * 128 + lane];
  float o1 = h1 * c - h2 * s;
  float o2 = h2 * c + h1 * s;
  if (isq) { o1 *= 0.088388347648318447f; o2 *= 0.088388347648318447f; }
  dst[lane] = f2bf(o1);
  dst[lane + 64] = f2bf(o2);
}

// ---------------- V transpose: qkv fp32 [.,3072] v-cols -> vT bf16 [B,KV,D,T] ----------------
__global__ __launch_bounds__(256) void v_trans(
    const float* __restrict__ qkv, u16* __restrict__ vT) {
  __shared__ u16 st[64][130];
  const int bi = blockIdx.x;  // b*128 + kv*32 + tt
  const int tt = bi & 31;
  const int kv = (bi >> 5) & 3;
  const int b = bi >> 7;
  const int tid = threadIdx.x;
#pragma unroll
  for (int i = 0; i < 32; ++i) {
    int idx = i * 256 + tid;
    int t = idx >> 7, d = idx & 127;
    float v = qkv[(size_t)(b * 2048 + tt * 64 + t) * 3072 + 2560 + kv * 128 + d];
    st[t][d] = f2bf(v);
  }
  __syncthreads();
#pragma unroll
  for (int i = 0; i < 32; ++i) {
    int idx = i * 256 + tid;
    int d = idx >> 6, t = idx & 63;
    vT[((size_t)(b * 4 + kv) * 128 + d) * 2048 + tt * 64 + t] = st[t][d];
  }
}

// ---------------- causal GQA flash attention (swapped 32x32 QK^T, in-register softmax) ----
// 4 warps x 32 q-rows = 128 q-rows/block. KVBLK=64. K dbuf in swizzled LDS.
// V direct from L2 (vT row-major). P assembled in-register (cvt_pk + permlane32_swap).
__global__ __launch_bounds__(256, 2) void attn(
    const u16* __restrict__ qhat, const u16* __restrict__ khat,
    const u16* __restrict__ vT, u16* __restrict__ yb) {
  __shared__ u16 Kt[2][64 * 128];
  // balanced remap: blocks j (c=0..7, light) and j+256 (c=15..8, heavy) share a CU
  const int bi = blockIdx.x;
  int bh, c;
  if (bi < 256) { bh = bi >> 3; c = bi & 7; }
  else          { bh = (bi - 256) >> 3; c = 15 - ((bi - 256) & 7); }
  const int h = bh & 15, b = bh >> 4;
  const int kvh = h >> 2;
  const int tid = threadIdx.x;
  const int w = tid >> 6, l = tid & 63;
  const int ql = l & 31;
  const int hi = l >> 5;
  const int q0 = c * 128;
  const int wq0 = q0 + w * 32;
  const int wq_end = wq0 + 31;
  const int qg = wq0 + ql;  // this lane's q row (for S^T columns)

  // Q fragments: B-operand of swapped QK^T. qf[s] = Q[qg][16s + 8hi .. +7]
  bf16x8 qf[8];
  const u16* qp = qhat + ((size_t)(b * 16 + h) * 2048 + qg) * 128 + hi * 8;
#pragma unroll
  for (int s = 0; s < 8; ++s) qf[s] = *(const bf16x8*)(qp + 16 * s);

  f32x16 yacc[4] = {};  // yacc[dblk]: lane holds y[wq0+crow(r,hi)][dblk*32+ql]
  float m = -1e30f, lsum = 0.f;

  const u16* Kg = khat + (size_t)(b * 4 + kvh) * 2048 * 128;
  const u16* Vg = vT + (size_t)(b * 4 + kvh) * 128 * 2048;
  const int nt = 2 * c + 2;
  const int srow = tid >> 4, schunk = tid & 15;

  // prologue: stage K tile 0 (pre-swizzled source, linear LDS dest)
#pragma unroll
  for (int cc = 0; cc < 4; ++cc) {
    int r = cc * 16 + srow;
    load_lds16(Kg + (size_t)r * 128 + (schunk ^ (r & 7)) * 8,
               &Kt[0][cc * 2048 + tid * 8]);
  }
  int cur = 0;
  for (int tile = 0; tile < nt; ++tile) {
    const int kv0 = tile * 64;
    __syncthreads();  // drains vmcnt: Kt[cur] ready
    if (tile + 1 < nt) {
#pragma unroll
      for (int cc = 0; cc < 4; ++cc) {
        int r = cc * 16 + srow;
        load_lds16(Kg + (size_t)(kv0 + 64 + r) * 128 + (schunk ^ (r & 7)) * 8,
                   &Kt[cur ^ 1][cc * 2048 + tid * 8]);
      }
    }
    if (kv0 <= wq_end) {  // warp-uniform causal skip
      // V B-frags for dblk 0,1 issued early (L2 latency hides under QK^T)
      const u16* Vrow = Vg + (size_t)ql * 2048 + kv0 + hi * 8;
      bf16x8 va[4], vb[4];
#pragma unroll
      for (int ks = 0; ks < 4; ++ks) va[ks] = *(const bf16x8*)(Vrow + ks * 16);
#pragma unroll
      for (int ks = 0; ks < 4; ++ks) vb[ks] = *(const bf16x8*)(Vrow + 32 * 2048 + ks * 16);
      // QK^T: S^T[kv][q] = K[kv][:] . Q[q][:]
      const u16* Kc = Kt[cur];
      f32x16 sacc[2] = {};
#pragma unroll
      for (int n = 0; n < 2; ++n) {
#pragma unroll
        for (int s = 0; s < 8; ++s) {
          bf16x8 kf = *(const bf16x8*)&Kc[(n * 32 + ql) * 128 + (((2 * s + hi) ^ (l & 7)) * 8)];
          sacc[n] = __builtin_amdgcn_mfma_f32_32x32x16_bf16(kf, qf[s], sacc[n], 0, 0, 0);
        }
      }
      // causal mask: needed on any tile not fully below this warp's diagonal.
      // (R3 bug: compared against wq_end — warps 1/3 left their diagonal tile
      //  unmasked when the tile end aligned with wq_end. Must compare wq0.)
      if (kv0 + 63 > wq0) {
#pragma unroll
        for (int n = 0; n < 2; ++n)
#pragma unroll
          for (int r = 0; r < 16; ++r) {
            int kv = kv0 + n * 32 + (r & 3) + 8 * (r >> 2) + 4 * hi;
            if (kv > qg) sacc[n][r] = -1e30f;
          }
      }
      // in-register online softmax (q = ql is lane-local; other kv half in lane^32)
      float pm = -1e30f;
#pragma unroll
      for (int n = 0; n < 2; ++n)
#pragma unroll
        for (int r = 0; r < 16; ++r) pm = fmaxf(pm, sacc[n][r]);
      pm = fmaxf(pm, __shfl_xor(pm, 32));
      if (!__all(pm - m <= 8.0f)) {  // defer-max: rescale only on real growth
        float mn = fmaxf(m, pm);
        float sc = __expf(m - mn);
        m = mn;
        lsum *= sc;
#pragma unroll
        for (int r = 0; r < 16; ++r) {
          int row = (r & 3) + 8 * (r >> 2) + 4 * hi;
          float scr = __shfl(sc, row);
#pragma unroll
          for (int d = 0; d < 4; ++d) yacc[d][r] *= scr;
        }
      }
      float ls = 0.f;
#pragma unroll
      for (int n = 0; n < 2; ++n)
#pragma unroll
        for (int r = 0; r < 16; ++r) {
          float e = __expf(sacc[n][r] - m);
          sacc[n][r] = e;
          ls += e;
        }
      ls += __shfl_xor(ls, 32);
      lsum += ls;
      // pack P -> A-frags: pa[ks] = P[q=ql][kv = 16ks + 8hi .. +7]
      bf16x8 pa[4];
#pragma unroll
      for (int s4 = 0; s4 < 4; ++s4) {
        const int n = s4 >> 1, R = (s4 & 1) * 8;
        unsigned P01 = cvtpk(sacc[n][R + 0], sacc[n][R + 1]);
        unsigned P23 = cvtpk(sacc[n][R + 2], sacc[n][R + 3]);
        unsigned P45 = cvtpk(sacc[n][R + 4], sacc[n][R + 5]);
        unsigned P67 = cvtpk(sacc[n][R + 6], sacc[n][R + 7]);
        plane32_swap(P01, P45);
        plane32_swap(P23, P67);
        union { u32x4 u; bf16x8 bv; } cvu;
        cvu.u[0] = P01; cvu.u[1] = P23; cvu.u[2] = P45; cvu.u[3] = P67;
        pa[s4] = cvu.bv;
      }
      // PV: yacc[dblk] += P * V (V frags for dblk 2,3 loaded mid-stream)
#pragma unroll
      for (int ks = 0; ks < 4; ++ks)
        yacc[0] = __builtin_amdgcn_mfma_f32_32x32x16_bf16(pa[ks], va[ks], yacc[0], 0, 0, 0);
#pragma unroll
      for (int ks = 0; ks < 4; ++ks) va[ks] = *(const bf16x8*)(Vrow + 64 * 2048 + ks * 16);
#pragma unroll
      for (int ks = 0; ks < 4; ++ks)
        yacc[1] = __builtin_amdgcn_mfma_f32_32x32x16_bf16(pa[ks], vb[ks], yacc[1], 0, 0, 0);
#pragma unroll
      for (int ks = 0; ks < 4; ++ks) vb[ks] = *(const bf16x8*)(Vrow + 96 * 2048 + ks * 16);
#pragma unroll
      for (int ks = 0; ks < 4; ++ks)
        yacc[2] = __builtin_amdgcn_mfma_f32_32x32x16_bf16(pa[ks], va[ks], yacc[2], 0, 0, 0);
#pragma unroll
      for (int ks = 0; ks < 4; ++ks)
        yacc[3] = __builtin_amdgcn_mfma_f32_32x32x16_bf16(pa[ks], vb[ks], yacc[3], 0, 0, 0);
    }
    cur ^= 1;
  }
  // epilogue: normalize and store y[b,t,h*128+d]
#pragma unroll
  for (int r = 0; r < 16; ++r) {
    int row = (r & 3) + 8 * (r >> 2) + 4 * hi;
    float li = __shfl(lsum, row);
    float inv = 1.0f / li;
    u16* yp = yb + ((size_t)(b * 2048) + wq0 + row) * 2048 + h * 128 + ql;
#pragma unroll
    for (int d = 0; d < 4; ++d) yp[d * 32] = f2bf(yacc[d][r] * inv);
  }
}

// ---------------- launcher ----------------

extern "C" void kernel_launch(void* const* d_in, const int* in_sizes, int n_in,
                              void* d_out, int out_size, void* d_ws, size_t ws_size,
                              hipStream_t stream) {
  const float* x    = (const float*)d_in[0];
  const float* Wq   = (const float*)d_in[1];
  const float* Wk   = (const float*)d_in[2];
  const float* Wv   = (const float*)d_in[3];
  const float* Wo   = (const float*)d_in[4];
  const float* qn   = (const float*)d_in[5];
  const float* kn   = (const float*)d_in[6];
  const float* cosb = (const float*)d_in[7];
  const float* sinb = (const float*)d_in[8];
  float* out = (float*)d_out;
  (void)in_sizes; (void)n_in; (void)out_size; (void)ws_size;

  char* p = (char*)d_ws;
  u16*   xb   = (u16*)p;   p += (size_t)8388608 * 2;    // x bf16 [4096,2048]
  u16*   wcat = (u16*)p;   p += (size_t)6291456 * 2;    // [3072,2048]
  u16*   wob  = (u16*)p;   p += (size_t)4194304 * 2;    // [2048,2048]
  float* qkvf = (float*)p; p += (size_t)12582912 * 4;   // [4096,3072] fp32
  u16*   qh   = (u16*)p;   p += (size_t)8388608 * 2;    // [2,16,2048,128]
  u16*   kh   = (u16*)p;   p += (size_t)2097152 * 2;    // [2,4,2048,128]
  u16*   vt   = (u16*)p;   p += (size_t)2097152 * 2;    // [2,4,128,2048]
  u16*   yb   = (u16*)p;   p += (size_t)8388608 * 2;    // [4096,2048]

  cvt_f32_bf16<<<2048, 256, 0, stream>>>(x, xb, 8388608);
  build_wcat<<<2048, 256, 0, stream>>>(Wq, Wk, Wv, wcat);
  cvt_f32_bf16<<<2048, 256, 0, stream>>>(Wo, wob, 4194304);
  gemm_bt<<<dim3(24, 32), 256, 0, stream>>>(xb, wcat, qkvf, 4096, 3072, 2048);
  norm_rope<<<20480, 256, 0, stream>>>(qkvf, qn, kn, cosb, sinb, qh, kh);
  v_trans<<<256, 256, 0, stream>>>(qkvf, vt);
  attn<<<512, 256, 0, stream>>>(qh, kh, vt, yb);
  gemm_bt<<<dim3(16, 32), 256, 0, stream>>>(yb, wob, out, 4096, 2048, 2048);
}